// Round 1
// baseline (840.504 us; speedup 1.0000x reference)
//
#include <hip/hip_runtime.h>
#include <hip/hip_bf16.h>
#include <math.h>

#define NGRAPH 64
#define NPG_   400
#define KSEL   250
#define FDIM   64
#define SEQ    12
#define LIN_   16000
#define HDIM   8000
#define NTOT   (NGRAPH*NPG_)   // 25600
#define BN_EPS 1e-5f
#define JBLK   32              // j columns per gemm block
#define NBLK   (HDIM/JBLK)     // 250

typedef float          floatx4  __attribute__((ext_vector_type(4)));
typedef unsigned int   uintx4   __attribute__((ext_vector_type(4)));
typedef unsigned short ushortx8 __attribute__((ext_vector_type(8)));
typedef __bf16         bf16x8   __attribute__((ext_vector_type(8)));

__device__ inline unsigned short f2bf(float x) {
    unsigned u = __float_as_uint(x);
    u += 0x7FFFu + ((u >> 16) & 1u);
    return (unsigned short)(u >> 16);
}

// ---------------------------------------------------------------------------
// Kernel 1: top-k pooling + tanh scaling + BatchNorm(eval) -> xn bf16 [64][16000]
// One block per graph. Exact stable top-k (descending, tie -> lower index)
// via rank = #{s_j > s_i} + #{j<i : s_j == s_i}.
// ---------------------------------------------------------------------------
__global__ __launch_bounds__(256) void pool_bn_kernel(
    const float* __restrict__ features, const float* __restrict__ w,
    const float* __restrict__ gamma, const float* __restrict__ beta,
    const float* __restrict__ mean, const float* __restrict__ var,
    unsigned short* __restrict__ xnA)
{
    __shared__ float s_w[FDIM];
    __shared__ float s_rnorm;
    __shared__ float s_score[NPG_];
    __shared__ int   s_idx[KSEL];
    __shared__ float s_scale[KSEL];

    const int g = blockIdx.x;
    const int t = threadIdx.x;
    const float* __restrict__ x = features + (size_t)(SEQ - 1) * NTOT * FDIM;

    if (t < FDIM) s_w[t] = w[t];
    __syncthreads();
    if (t == 0) {
        float s = 0.f;
        #pragma unroll
        for (int i = 0; i < FDIM; ++i) s += s_w[i] * s_w[i];
        s_rnorm = 1.0f / sqrtf(s);
    }
    __syncthreads();
    const float rnorm = s_rnorm;

    for (int i = t; i < NPG_; i += 256) {
        const floatx4* xr = (const floatx4*)(x + (size_t)(g * NPG_ + i) * FDIM);
        float s = 0.f;
        #pragma unroll
        for (int q = 0; q < FDIM / 4; ++q) {
            floatx4 v = xr[q];
            s += v[0]*s_w[4*q] + v[1]*s_w[4*q+1] + v[2]*s_w[4*q+2] + v[3]*s_w[4*q+3];
        }
        s_score[i] = s * rnorm;
    }
    __syncthreads();

    for (int i = t; i < NPG_; i += 256) {
        const float si = s_score[i];
        int r = 0;
        for (int jj = 0; jj < NPG_; ++jj) {
            const float sj = s_score[jj];
            r += (sj > si) || (sj == si && jj < i);
        }
        if (r < KSEL) { s_idx[r] = i; s_scale[r] = tanhf(si); }
    }
    __syncthreads();

    const size_t rowbase = (size_t)g * LIN_;
    for (int c = t; c < LIN_; c += 256) {
        const int p = c >> 6, f = c & 63;
        const int node = g * NPG_ + s_idx[p];
        const float v = x[(size_t)node * FDIM + f] * s_scale[p];
        const float xnv = (v - mean[c]) * rsqrtf(var[c] + BN_EPS) * gamma[c] + beta[c];
        xnA[rowbase + c] = f2bf(xnv);
    }
}

// ---------------------------------------------------------------------------
// Kernel 2: h = relu(xn @ W1^T + b1); partial[blk][b] = sum_{j in blk} h*W2[j]
// 250 blocks x 256 threads. Wave w: j-tile = w>>1, k-parity = w&1.
// B (W1 fp32) loaded global->reg, cvt to bf16 in-regs. A (xn bf16) from L2.
// mfma_f32_16x16x32_bf16: A[m=lane&15][k=(lane>>4)*8+j], B[n=lane&15][k=...],
// D col = lane&15 (j), row = (lane>>4)*4 + reg (b).
// ---------------------------------------------------------------------------
__global__ __launch_bounds__(256) void gemm_kernel(
    const float* __restrict__ W1, const unsigned short* __restrict__ xnA,
    const float* __restrict__ b1, const float* __restrict__ W2,
    float* __restrict__ partials)
{
    const int t = threadIdx.x;
    const int wave = t >> 6, lane = t & 63;
    const int jt = wave >> 1, par = wave & 1;
    const int blk = blockIdx.x;
    const int n = lane & 15, kg = lane >> 4;
    const int j = blk * JBLK + jt * 16 + n;

    const size_t boff  = (size_t)j * LIN_ + kg * 8;
    const size_t aoff0 = (size_t)(n)      * LIN_ + kg * 8;
    const size_t aoff1 = aoff0 + (size_t)16 * LIN_;
    const size_t aoff2 = aoff1 + (size_t)16 * LIN_;
    const size_t aoff3 = aoff2 + (size_t)16 * LIN_;

    floatx4 acc0 = {0,0,0,0}, acc1 = {0,0,0,0}, acc2 = {0,0,0,0}, acc3 = {0,0,0,0};

    int k = par * 32;
    floatx4 pb0 = *(const floatx4*)(W1 + boff + k);
    floatx4 pb1 = *(const floatx4*)(W1 + boff + k + 4);
    uintx4  pa0 = *(const uintx4*)(xnA + aoff0 + k);
    uintx4  pa1 = *(const uintx4*)(xnA + aoff1 + k);
    uintx4  pa2 = *(const uintx4*)(xnA + aoff2 + k);
    uintx4  pa3 = *(const uintx4*)(xnA + aoff3 + k);

    for (int s = 0; s < 250; ++s) {
        const int kn = k + 64;
        const int kl = (s < 249) ? kn : par * 32;  // last iter: dummy in-cache load
        floatx4 nb0 = *(const floatx4*)(W1 + boff + kl);
        floatx4 nb1 = *(const floatx4*)(W1 + boff + kl + 4);
        uintx4  na0 = *(const uintx4*)(xnA + aoff0 + kl);
        uintx4  na1 = *(const uintx4*)(xnA + aoff1 + kl);
        uintx4  na2 = *(const uintx4*)(xnA + aoff2 + kl);
        uintx4  na3 = *(const uintx4*)(xnA + aoff3 + kl);

        ushortx8 bs;
        bs[0] = f2bf(pb0[0]); bs[1] = f2bf(pb0[1]); bs[2] = f2bf(pb0[2]); bs[3] = f2bf(pb0[3]);
        bs[4] = f2bf(pb1[0]); bs[5] = f2bf(pb1[1]); bs[6] = f2bf(pb1[2]); bs[7] = f2bf(pb1[3]);
        const bf16x8 bfrag = __builtin_bit_cast(bf16x8, bs);

        acc0 = __builtin_amdgcn_mfma_f32_16x16x32_bf16(__builtin_bit_cast(bf16x8, pa0), bfrag, acc0, 0, 0, 0);
        acc1 = __builtin_amdgcn_mfma_f32_16x16x32_bf16(__builtin_bit_cast(bf16x8, pa1), bfrag, acc1, 0, 0, 0);
        acc2 = __builtin_amdgcn_mfma_f32_16x16x32_bf16(__builtin_bit_cast(bf16x8, pa2), bfrag, acc2, 0, 0, 0);
        acc3 = __builtin_amdgcn_mfma_f32_16x16x32_bf16(__builtin_bit_cast(bf16x8, pa3), bfrag, acc3, 0, 0, 0);

        pb0 = nb0; pb1 = nb1;
        pa0 = na0; pa1 = na1; pa2 = na2; pa3 = na3;
        k = kn;
    }

    __shared__ float hbuf[64][33];
    const int col  = jt * 16 + n;
    const int mrow = kg * 4;
    if (par == 0) {
        #pragma unroll
        for (int r = 0; r < 4; ++r) {
            hbuf[ 0 + mrow + r][col] = acc0[r];
            hbuf[16 + mrow + r][col] = acc1[r];
            hbuf[32 + mrow + r][col] = acc2[r];
            hbuf[48 + mrow + r][col] = acc3[r];
        }
    }
    __syncthreads();
    if (par == 1) {
        #pragma unroll
        for (int r = 0; r < 4; ++r) {
            hbuf[ 0 + mrow + r][col] += acc0[r];
            hbuf[16 + mrow + r][col] += acc1[r];
            hbuf[32 + mrow + r][col] += acc2[r];
            hbuf[48 + mrow + r][col] += acc3[r];
        }
    }
    __syncthreads();

    const int m = t >> 2, jq = t & 3;
    float s = 0.f;
    #pragma unroll
    for (int q = 0; q < 8; ++q) {
        const int jj = jq * 8 + q;
        float h = hbuf[m][jj] + b1[blk * JBLK + jj];
        h = fmaxf(h, 0.f);
        s += h * W2[blk * JBLK + jj];
    }
    s += __shfl_xor(s, 1);
    s += __shfl_xor(s, 2);
    if (jq == 0) partials[blk * 64 + m] = s;
}

// ---------------------------------------------------------------------------
// Kernel 3: logits[b] = sum_blk partial + b2; loss = mean softplus(-logit)
// ---------------------------------------------------------------------------
__global__ __launch_bounds__(64) void loss_kernel(
    const float* __restrict__ partials, const float* __restrict__ b2,
    float* __restrict__ out)
{
    const int b = threadIdx.x;  // 0..63
    float l = b2[0];
    for (int i = 0; i < NBLK; ++i) l += partials[i * 64 + b];
    // softplus(l) - l = softplus(-l) = max(-l,0) + log1p(exp(-|l|))
    float ls = fmaxf(-l, 0.f) + log1pf(expf(-fabsf(l)));
    #pragma unroll
    for (int d = 1; d < 64; d <<= 1) ls += __shfl_xor(ls, d);
    if (b == 0) out[0] = ls * (1.0f / 64.0f);
}

extern "C" void kernel_launch(void* const* d_in, const int* in_sizes, int n_in,
                              void* d_out, int out_size, void* d_ws, size_t ws_size,
                              hipStream_t stream)
{
    const float* features = (const float*)d_in[0];
    // d_in[1] edge_index, d_in[2] batch: unused by the reference computation
    const float* w     = (const float*)d_in[3];
    const float* gamma = (const float*)d_in[4];
    const float* beta  = (const float*)d_in[5];
    const float* mean  = (const float*)d_in[6];
    const float* var   = (const float*)d_in[7];
    const float* W1    = (const float*)d_in[8];
    const float* b1    = (const float*)d_in[9];
    const float* W2    = (const float*)d_in[10];
    const float* b2    = (const float*)d_in[11];

    unsigned short* xnA = (unsigned short*)d_ws;                 // 64*16000*2 = 2,048,000 B
    float* partials = (float*)((char*)d_ws + 2048000);           // 250*64*4  =    64,000 B

    pool_bn_kernel<<<NGRAPH, 256, 0, stream>>>(features, w, gamma, beta, mean, var, xnA);
    gemm_kernel<<<NBLK, 256, 0, stream>>>(W1, xnA, b1, W2, partials);
    loss_kernel<<<1, 64, 0, stream>>>(partials, b2, (float*)d_out);
}